// Round 9
// baseline (142.189 us; speedup 1.0000x reference)
//
#include <hip/hip_runtime.h>
#include <hip/hip_bf16.h>

// Problem constants
#define NB   32      // batch
#define NC   24      // image channels
#define ND   12      // spatial
#define NN   144     // ND*ND objects
#define QD   11
#define GH   256
#define FOUT 10
#define BPB  16      // blocks per batch (512 total = 2/CU)

typedef unsigned short u16;
typedef __attribute__((ext_vector_type(8))) short bf16x8;
typedef __attribute__((ext_vector_type(4))) float f32x4;

// Workspace layout:
//   Lq  f32 [32][144][256]  float-off 0         (= L + q@Wg1_q + bg1 folded)
//   R   f32 [32][144][256]  float-off 1179648
//   S   f32 [32][256]       float-off 2359296
//   Bswz u16 [128][64][8]   u16-off  4734976    (MFMA B-fragment order)
#define LQ_OFF  0
#define R_OFF   1179648
#define S_OFF   2359296
#define BS_U16  4734976

__device__ inline u16 f2b(float f) {
  __hip_bfloat16 h = __float2bfloat16(f);
  return *reinterpret_cast<u16*>(&h);
}

// ---------------------------------------------------------------------------
// Fused prep (f32 Lq/R):
//  blocks [0, 9216): per-object projections (Lq folds q-term + bg1).
//  blocks [9216, 9472): Wg2 -> bf16 B-fragment swizzle; zero S.
// ---------------------------------------------------------------------------
__global__ __launch_bounds__(256) void prep(const float* __restrict__ image,
                                            const float* __restrict__ question,
                                            const float* __restrict__ Wg1,
                                            const float* __restrict__ bg1,
                                            const float* __restrict__ Wg2,
                                            float* __restrict__ Lq,
                                            float* __restrict__ R,
                                            float* __restrict__ S,
                                            u16* __restrict__ Bswz) {
  int blk = blockIdx.x;
  int h   = threadIdx.x;
  if (blk < 2 * NB * NN) {
    int p     = blk % NN;
    int rest2 = blk / NN;
    int b     = rest2 & (NB - 1);
    int which = rest2 >> 5;
    const float* Wrow = Wg1 + which * (NC + 2) * GH;
    const float* img  = image + b * (NC * NN) + p;
    float acc = 0.f;
#pragma unroll
    for (int c = 0; c < NC; ++c) acc += img[c * NN] * Wrow[c * GH + h];
    int i = p / ND, j = p - i * ND;
    const float inv = 1.0f / (ND - 1);
    acc += (j * inv) * Wrow[24 * GH + h];
    acc += (i * inv) * Wrow[25 * GH + h];
    if (which == 0) {
      acc += bg1[h];
#pragma unroll
      for (int tq = 0; tq < QD; ++tq)
        acc += question[b * QD + tq] * Wg1[(2 * (NC + 2) + tq) * GH + h];
      Lq[(b * NN + p) * GH + h] = acc;
    } else {
      R[(b * NN + p) * GH + h] = acc;
    }
  } else {
    int tid = (blk - 2 * NB * NN) * 256 + h;   // 0..65535
    int e   = tid & 7;
    int l   = (tid >> 3) & 63;
    int fid = tid >> 9;
    int kt  = fid >> 4, nt = fid & 15;
    int k = kt * 32 + ((l >> 4) << 3) + e;
    int n = (nt << 4) + (l & 15);
    Bswz[tid] = f2b(Wg2[k * GH + n]);
    if (tid < NB * GH) S[tid] = 0.f;
  }
}

// ---------------------------------------------------------------------------
// MFMA pair GEMM v9: persistent blocks, tile-level double-buffered LDS, build
// of tile t+1 interleaved into tile t's MFMA stream — with an EXPLICIT
// depth-1 per-octet register ring (statically indexed under full unroll) so
// the compiler cannot invent a register-hungry pipeline and spill.
// Per q: {4 af ds_reads; ring loads for octet q+1; 4 bfr loads; 16 MFMA;
// build math octet q (f32x4 pk add/max + cvt) + swizzled ds_write}.
// ONE barrier per tile. Grid = 512 blocks (2/CU), XCD-pinned batches.
// ---------------------------------------------------------------------------
__global__ __launch_bounds__(256, 2) void pair_gemm(const float* __restrict__ Lq,
                                                    const float* __restrict__ R,
                                                    const u16* __restrict__ Bswz,
                                                    const float* __restrict__ bg2,
                                                    float* __restrict__ S) {
  const int bid = blockIdx.x;          // 0..511
  const int xcd = bid & 7;
  const int idx = bid >> 3;            // 0..63
  const int b   = xcd * 4 + (idx >> 4);
  const int bi  = idx & 15;
  const int t0  = bi * 20 + (bi < 4 ? bi : 4);   // 4 blocks: 21 tiles, 12: 20
  const int cnt = 20 + (bi < 4 ? 1 : 0);

  __shared__ __align__(16) u16 As[2][16384];     // 2 x 32 KB fragment layout

  const int t = threadIdx.x;
  const int w = t >> 6, l = t & 63;
  const int brow = t >> 2, c = t & 3;            // build role: row, k-octet
  const int lane_w = ((brow & 15) | (c << 4)) ^ (c << 1);  // 2-way swizzle
  const int mf_w   = brow >> 4;
  const int lane_r = l ^ (((l >> 4) & 3) << 1);

  const float* Lbase = Lq + b * NN * GH;
  const float* Rbase = R + b * NN * GH;
  const u16*   Bl    = Bswz + l * 8;

  float bgv[4];
#pragma unroll
  for (int ntl = 0; ntl < 4; ++ntl)
    bgv[ntl] = bg2[(w << 6) + (ntl << 4) + (l & 15)];
  float ssum[4] = {0.f, 0.f, 0.f, 0.f};

  // Prologue: build tile t0 fully into As[0] (vector math, latency exposed once)
  {
    int p = t0 * 64 + brow;
    int i = p / NN, j = p - i * NN;
    const float* Lr = Lbase + i * GH + c * 8;
    const float* Rr = Rbase + j * GH + c * 8;
#pragma unroll
    for (int q = 0; q < 8; ++q) {
      f32x4 s0 = *(const f32x4*)(Lr + q * 32)     + *(const f32x4*)(Rr + q * 32);
      f32x4 s1 = *(const f32x4*)(Lr + q * 32 + 4) + *(const f32x4*)(Rr + q * 32 + 4);
      s0 = __builtin_elementwise_max(s0, (f32x4)0.f);
      s1 = __builtin_elementwise_max(s1, (f32x4)0.f);
      u16 o[8];
#pragma unroll
      for (int e = 0; e < 4; ++e) { o[e] = f2b(s0[e]); o[e + 4] = f2b(s1[e]); }
      *(bf16x8*)&As[0][((((q << 2) | mf_w) << 6) | lane_w) << 3] = *(bf16x8*)o;
    }
  }
  __syncthreads();

  for (int tt = 0; tt < cnt; ++tt) {
    const int  cur = tt & 1;
    const bool hb  = (tt + 1 < cnt);
    const float* Lb = Lbase;
    const float* Rb = Rbase;
    if (hb) {
      int p = (t0 + tt + 1) * 64 + brow;
      int i = p / NN, j = p - i * NN;
      Lb = Lbase + i * GH + c * 8;
      Rb = Rbase + j * GH + c * 8;
    }
    // depth-1 build ring (statically indexed after unroll)
    f32x4 rl0[2], rl1[2], rr0[2], rr1[2];
    if (hb) {
      rl0[0] = *(const f32x4*)(Lb);
      rl1[0] = *(const f32x4*)(Lb + 4);
      rr0[0] = *(const f32x4*)(Rb);
      rr1[0] = *(const f32x4*)(Rb + 4);
    }
    f32x4 acc[4][4] = {};
#pragma unroll
    for (int q = 0; q < 8; ++q) {
      // A fragments for this group (swizzle-read)
      bf16x8 af[4];
#pragma unroll
      for (int mf = 0; mf < 4; ++mf)
        af[mf] = *(const bf16x8*)&As[cur][((((q << 2) | mf) << 6) | lane_r) << 3];
      // ring loads for build octet q+1
      if (hb && q < 7) {
        rl0[(q + 1) & 1] = *(const f32x4*)(Lb + (q + 1) * 32);
        rl1[(q + 1) & 1] = *(const f32x4*)(Lb + (q + 1) * 32 + 4);
        rr0[(q + 1) & 1] = *(const f32x4*)(Rb + (q + 1) * 32);
        rr1[(q + 1) & 1] = *(const f32x4*)(Rb + (q + 1) * 32 + 4);
      }
      // B fragments (L2-resident)
      bf16x8 bfr[4];
#pragma unroll
      for (int ntl = 0; ntl < 4; ++ntl) {
        int fid = (q << 4) | (w << 2) | ntl;
        bfr[ntl] = *(const bf16x8*)(Bl + ((size_t)fid << 9));
      }
      // 16 MFMAs (previous q's pipe execution covers these loads' latency)
#pragma unroll
      for (int mf = 0; mf < 4; ++mf)
#pragma unroll
        for (int ntl = 0; ntl < 4; ++ntl)
          acc[mf][ntl] = __builtin_amdgcn_mfma_f32_16x16x32_bf16(
              af[mf], bfr[ntl], acc[mf][ntl], 0, 0, 0);
      // build math octet q (data loaded at q-1), swizzled ds_write
      if (hb) {
        f32x4 s0 = rl0[q & 1] + rr0[q & 1];
        f32x4 s1 = rl1[q & 1] + rr1[q & 1];
        s0 = __builtin_elementwise_max(s0, (f32x4)0.f);
        s1 = __builtin_elementwise_max(s1, (f32x4)0.f);
        u16 o[8];
#pragma unroll
        for (int e = 0; e < 4; ++e) { o[e] = f2b(s0[e]); o[e + 4] = f2b(s1[e]); }
        *(bf16x8*)&As[cur ^ 1][((((q << 2) | mf_w) << 6) | lane_w) << 3] =
            *(bf16x8*)o;
      }
    }
    // per-tile epilogue: fold relu(acc + bg2) into running sums
#pragma unroll
    for (int ntl = 0; ntl < 4; ++ntl) {
      float s = 0.f;
#pragma unroll
      for (int mf = 0; mf < 4; ++mf)
#pragma unroll
        for (int r = 0; r < 4; ++r) {
          float v = acc[mf][ntl][r] + bgv[ntl];
          s += v > 0.f ? v : 0.f;
        }
      ssum[ntl] += s;
    }
    __syncthreads();
  }

  // Final reduce: C/D col = l&15; shfl-reduce rows, one atomic per col slice
  float* Sb = S + b * GH;
#pragma unroll
  for (int ntl = 0; ntl < 4; ++ntl) {
    float s = ssum[ntl];
    s += __shfl_xor(s, 16, 64);
    s += __shfl_xor(s, 32, 64);
    if (l < 16) atomicAdd(&Sb[(w << 6) + (ntl << 4) + (l & 15)], s);
  }
}

// ---------------------------------------------------------------------------
// Final f-MLP: out = relu(S@Wf1+bf1)@Wf2+bf2. One block per batch.
// ---------------------------------------------------------------------------
__global__ __launch_bounds__(256) void final_mlp(const float* __restrict__ S,
                                                 const float* __restrict__ Wf1,
                                                 const float* __restrict__ bf1,
                                                 const float* __restrict__ Wf2,
                                                 const float* __restrict__ bf2,
                                                 float* __restrict__ out) {
  __shared__ float sS[GH];
  __shared__ float oS[GH];
  int b = blockIdx.x, h = threadIdx.x;
  sS[h] = S[b * GH + h];
  __syncthreads();
  float acc = bf1[h];
#pragma unroll 8
  for (int k = 0; k < GH; ++k) acc += sS[k] * Wf1[k * GH + h];
  oS[h] = acc > 0.f ? acc : 0.f;
  __syncthreads();
  if (h < FOUT) {
    float o = bf2[h];
#pragma unroll 8
    for (int k = 0; k < GH; ++k) o += oS[k] * Wf2[k * FOUT + h];
    out[b * FOUT + h] = o;
  }
}

extern "C" void kernel_launch(void* const* d_in, const int* in_sizes, int n_in,
                              void* d_out, int out_size, void* d_ws, size_t ws_size,
                              hipStream_t stream) {
  const float* image    = (const float*)d_in[0];
  const float* question = (const float*)d_in[1];
  const float* Wg1      = (const float*)d_in[2];
  const float* bg1      = (const float*)d_in[3];
  const float* Wg2      = (const float*)d_in[4];
  const float* bg2      = (const float*)d_in[5];
  const float* Wf1      = (const float*)d_in[6];
  const float* bf1      = (const float*)d_in[7];
  const float* Wf2      = (const float*)d_in[8];
  const float* bf2      = (const float*)d_in[9];
  float* out = (float*)d_out;

  float* wsf  = (float*)d_ws;
  float* Lqp  = wsf + LQ_OFF;
  float* Rp   = wsf + R_OFF;
  float* Sp   = wsf + S_OFF;
  u16*   Bswz = (u16*)d_ws + BS_U16;

  prep<<<2 * NB * NN + 256, 256, 0, stream>>>(image, question, Wg1, bg1, Wg2,
                                              Lqp, Rp, Sp, Bswz);
  pair_gemm<<<NB * BPB, 256, 0, stream>>>(Lqp, Rp, Bswz, bg2, Sp);
  final_mlp<<<NB, 256, 0, stream>>>(Sp, Wf1, bf1, Wf2, bf2, out);
}